// Round 1
// baseline (1830.198 us; speedup 1.0000x reference)
//
#include <hip/hip_runtime.h>

// Furthest Point Sampling, B=8, C=3, N=65536, NUM_POINTS=1024.
//
// R10 = R9's measured-XCD placement + L2 exchange, restructured to be fully
// WAVE-AUTONOMOUS. Evidence from R9's counters: 1.59us/iter with VALUBusy=12%
// -> ~85% of each iteration is serial exchange latency, and ~600-900cy of it
// is intra-block serialization (syncthreads + LDS key hop + wave0 2-step
// reduce + LDS mailbox fanout) plus a ~300cy DEPENDENT winner-coords uniform
// load at the end of the chain. None of that is fundamental.
//
// Changes vs R9:
//  * Per-WAVE publish: 64 slots/batch (slice*4+wave), published by each
//    wave's lane 0 straight after the wave butterfly. No __syncthreads, no
//    s_wkey hop, no block reduce -> the batch's last publish happens ~300cy
//    earlier.
//  * Every wave polls all 64 slots itself (lane l <-> slot l) and does the
//    6-step butterfly -> no LDS mailbox; all waves receive the winner at poll
//    exit + reduce latency.
//  * Speculative coord gather: after poll exit, each lane issues x/y/z loads
//    for ITS OWN slot's candidate index (3 independent L2-hot loads). They
//    complete underneath the 6-step reduce butterfly; the winner's coords are
//    then extracted with one ballot + 3 shfl (~50cy) instead of a dependent
//    s_load chain (~300cy, K$-missing every iteration).
//  * The only remaining per-iteration serial pieces: compute (~380cy), wave
//    butterfly (~300cy), sc0 store->L2 visibility + poll round quantization
//    (the R3/R6/R8-measured transport floor), reduce butterfly (~300cy).
//
// Placement (init, once, unchanged from R9): 256 blocks; each reads its
// physical XCD id via s_getreg(HW_REG_XCC_ID) and registers on a per-XCD
// counter; first 16 registrants on XCD j own batch j. Late blocks become
// spares covering vacancies (cross-XCD, served by the IC fallback line).
//
// Exchange lines per region: line A (sc0 -> home XCD's L2, the intra-XCD
// coherence point) polled from round 0; line B (agent-scope -> IC) merged
// from round 2 so progress NEVER depends on placement.
//
// Regions rotate mod 8. The poll is a batch-wide barrier, so a wave can lead
// the slowest wave by at most 1 iteration -> writer region (it+1)&7 never
// collides with a reader at it&7. Tags self-validate slots: key low 16 bits
// == it; 0xAA poison = tag 0xAAAA never matches it < 1024; cross-launch stale
// tags can only match for the SAME it, whose key is value-identical (FPS is
// deterministic) -> no memset of slots needed (only the 64B ctrl block).
//
// Key packing (idx < 65536): dist_bits(32) | (0xFFFF - idx)(16) | it(16).
// Max key = max dist, tie -> smaller index == jnp.argmax first-occurrence
// (dist >= 0 -> float bits monotone; same tag on all keys of an iteration).
// Distance math: __fmul_rn/__fadd_rn (no FMA contraction) to bit-match numpy.

namespace {

constexpr int kB = 8;
constexpr int kN = 65536;
constexpr int kNP = 1024;
constexpr int kPB = 16;                      // slices (blocks) per batch
constexpr int kThreads = 256;
constexpr int kPPT = kN / (kPB * kThreads);  // 16 points per thread
constexpr int kGrp = kPPT / 4;               // 4 float4 groups
constexpr int kWaves = kThreads / 64;        // 4
constexpr int kSlots = kPB * kWaves;         // 64 publish slots per batch
constexpr int kRgn = 8;                      // region rotation depth (skew <= 1)
constexpr int kRgnStride = 2 * kSlots;       // u64s: [0,64)=line A (L2), [64,128)=line B (IC)
constexpr int kBatchStride = kRgn * kRgnStride;  // 1024 u64 = 8 KB per batch
constexpr int kBlocks = kB * kPB;            // 256

__device__ __forceinline__ unsigned long long shfl_xor_u64(unsigned long long v, int off) {
  return (unsigned long long)__shfl_xor((long long)v, off, 64);
}

__device__ __forceinline__ unsigned long long u64max(unsigned long long a,
                                                     unsigned long long b) {
  return a > b ? a : b;
}

// sc0 load: bypass L1, served by this XCD's L2 (the intra-XCD coherence point).
__device__ __forceinline__ unsigned long long load_l2(const unsigned long long* p) {
  unsigned long long v;
  asm volatile("global_load_dwordx2 %0, %1, off sc0\n\ts_waitcnt vmcnt(0)"
               : "=v"(v)
               : "v"(p)
               : "memory");
  return v;
}

// sc0 store: write-through to this XCD's L2.
__device__ __forceinline__ void store_l2(unsigned long long* p, unsigned long long v) {
  asm volatile("global_store_dwordx2 %0, %1, off sc0" ::"v"(p), "v"(v) : "memory");
}

__global__ __launch_bounds__(kThreads) void fps_kernel(const float* __restrict__ pts,
                                                       float* __restrict__ out,
                                                       unsigned long long* __restrict__ slots,
                                                       unsigned* __restrict__ ctrl) {
  // ctrl: [0:8) per-XCD registration counters, [8] done count, [9] spare rank.
  const int tid = threadIdx.x;
  const int lane = tid & 63;
  const int wave = tid >> 6;

  __shared__ int s_batch, s_slice;
  __shared__ int s_hist[kNP];

  if (tid == 0) {
    unsigned xcc;
    asm volatile("s_getreg_b32 %0, hwreg(HW_REG_XCC_ID)" : "=s"(xcc));
    const int home = (int)(xcc & 7u);
    int batch = -1, slice = -1;
    const int pos = (int)atomicAdd(&ctrl[home], 1u);
    if (pos < kPB) {
      batch = home;
      slice = pos;
    }
    __hip_atomic_fetch_add(&ctrl[8], 1u, __ATOMIC_RELEASE, __HIP_MEMORY_SCOPE_AGENT);
    if (batch < 0) {
      while (__hip_atomic_load(&ctrl[8], __ATOMIC_ACQUIRE, __HIP_MEMORY_SCOPE_AGENT) <
             (unsigned)kBlocks) {
        __builtin_amdgcn_s_sleep(8);
      }
      int need = (int)atomicAdd(&ctrl[9], 1u);
      for (int j = 0; j < kB; ++j) {
        int have = (int)__hip_atomic_load(&ctrl[j], __ATOMIC_RELAXED, __HIP_MEMORY_SCOPE_AGENT);
        have = have > kPB ? kPB : have;
        const int vac = kPB - have;
        if (need < vac) {
          batch = j;
          slice = have + need;
          break;
        }
        need -= vac;
      }
    }
    s_batch = batch;
    s_slice = slice;
  }
  __syncthreads();

  const int batch = s_batch;
  const int slice = s_slice;
  if (batch < 0) return;  // unneeded spare

  const float* __restrict__ xb = pts + (size_t)batch * 3 * kN;
  const float* __restrict__ yb = xb + kN;
  const float* __restrict__ zb = xb + 2 * kN;

  // Register-resident coords: block owns [slice*4096, slice*4096+4096).
  const int sbase = slice * (kThreads * kPPT);
  const int base0 = sbase + tid * 4;
  float px[kPPT], py[kPPT], pz[kPPT], dist[kPPT];
#pragma unroll
  for (int g = 0; g < kGrp; ++g) {
    const int base = base0 + g * (kThreads * 4);
    const float4 vx = *reinterpret_cast<const float4*>(xb + base);
    const float4 vy = *reinterpret_cast<const float4*>(yb + base);
    const float4 vz = *reinterpret_cast<const float4*>(zb + base);
    px[g * 4 + 0] = vx.x; px[g * 4 + 1] = vx.y; px[g * 4 + 2] = vx.z; px[g * 4 + 3] = vx.w;
    py[g * 4 + 0] = vy.x; py[g * 4 + 1] = vy.y; py[g * 4 + 2] = vy.z; py[g * 4 + 3] = vy.w;
    pz[g * 4 + 0] = vz.x; pz[g * 4 + 1] = vz.y; pz[g * 4 + 2] = vz.z; pz[g * 4 + 3] = vz.w;
  }
#pragma unroll
  for (int k = 0; k < kPPT; ++k) dist[k] = 1e10f;

  // Seed: index 0 (uniform broadcast load).
  float qx = xb[0], qy = yb[0], qz = zb[0];

  unsigned long long* const sb = slots + (size_t)batch * kBatchStride;
  const int slot = slice * kWaves + wave;  // this wave's publish slot, [0,64)

  for (int it = 1; it < kNP; ++it) {
    // --- update dists + per-thread argmax (ascending index, strict '>') ---
    float bd = -1.0f;
    int bi = 0;
#pragma unroll
    for (int g = 0; g < kGrp; ++g) {
#pragma unroll
      for (int j = 0; j < 4; ++j) {
        const int k = g * 4 + j;
        const float dx = px[k] - qx;
        const float dy = py[k] - qy;
        const float dz = pz[k] - qz;
        const float ss =
            __fadd_rn(__fadd_rn(__fmul_rn(dx, dx), __fmul_rn(dy, dy)), __fmul_rn(dz, dz));
        const float nd = fminf(dist[k], ss);
        dist[k] = nd;
        if (nd > bd) {
          bd = nd;
          bi = base0 + g * (kThreads * 4) + j;
        }
      }
    }

    // key: dist(32) | (0xFFFF - idx)(16) | it(16)  -- tag self-validates slots.
    unsigned long long key = ((unsigned long long)__float_as_uint(bd) << 32) |
                             ((unsigned long long)(0xFFFFu - (unsigned)bi) << 16) |
                             (unsigned long long)(unsigned)it;

    // --- wave butterfly (6 steps) ---
#pragma unroll
    for (int off = 32; off > 0; off >>= 1) {
      key = u64max(key, shfl_xor_u64(key, off));
    }

    unsigned long long* const rgn = sb + (size_t)(it & (kRgn - 1)) * kRgnStride;

    // --- per-wave publish, straight off the butterfly (no block reduce) ---
    if (lane == 0) {
      store_l2(rgn + slot, key);  // primary: XCD-local L2 (measured co-location)
      __hip_atomic_store(rgn + kSlots + slot, key, __ATOMIC_RELAXED,
                         __HIP_MEMORY_SCOPE_AGENT);  // fallback: IC
    }

    // --- every wave polls all 64 slots (lane l <-> slot l) ---
    unsigned long long w;
    int round = 0;
    for (;;) {
      unsigned long long a = load_l2(rgn + lane);
      bool ok = (unsigned)(a & 0xFFFFull) == (unsigned)it;
      if (round >= 2 && !ok) {
        const unsigned long long fb = __hip_atomic_load(
            rgn + kSlots + lane, __ATOMIC_RELAXED, __HIP_MEMORY_SCOPE_AGENT);
        if ((unsigned)(fb & 0xFFFFull) == (unsigned)it) {
          a = fb;
          ok = true;
        }
      }
      if (__all(ok)) {
        w = a;
        break;
      }
      ++round;
    }

    // --- speculative candidate-coord gather: issued BEFORE the reduce
    //     butterfly, completes underneath it (L2-hot, ~225cy < ~300cy) ---
    const int cand = (int)(0xFFFFu - ((unsigned)(w >> 16) & 0xFFFFu));
    const float gx = xb[cand];
    const float gy = yb[cand];
    const float gz = zb[cand];

    // --- 6-step reduce butterfly over the 64 slot keys ---
    unsigned long long k2 = w;
#pragma unroll
    for (int off = 32; off > 0; off >>= 1) {
      k2 = u64max(k2, shfl_xor_u64(k2, off));
    }

    // Winner's coords: slot keys are globally unique (disjoint index ranges),
    // so exactly one lane holds k2; pull its speculative gather via shfl.
    const int src = (int)__ffsll((unsigned long long)__ballot(k2 == w)) - 1;
    qx = __shfl(gx, src, 64);
    qy = __shfl(gy, src, 64);
    qz = __shfl(gz, src, 64);

    if (tid == 0) s_hist[it] = (int)(0xFFFFu - ((unsigned)(k2 >> 16) & 0xFFFFu));
  }

  __syncthreads();  // make s_hist (written by wave 0) visible to all waves

  // --- gather: out[b][c][j] = points[b][c][idx_j]; slice-0 block per batch ---
  if (slice == 0) {
    float* __restrict__ ob = out + (size_t)batch * 3 * kNP;
    for (int j = tid; j < kNP; j += kThreads) {
      const int id = (j == 0) ? 0 : s_hist[j];
      ob[j] = xb[id];
      ob[kNP + j] = yb[id];
      ob[2 * kNP + j] = zb[id];
    }
  }
}

}  // namespace

extern "C" void kernel_launch(void* const* d_in, const int* in_sizes, int n_in,
                              void* d_out, int out_size, void* d_ws, size_t ws_size,
                              hipStream_t stream) {
  (void)in_sizes;
  (void)n_in;
  (void)out_size;
  (void)ws_size;
  const float* pts = (const float*)d_in[0];
  float* out = (float*)d_out;
  // ws: [0,64) ctrl (zeroed per launch), [1024, 1024+64K) slot regions
  // (tag-validated: 0xAA poison -> tag 0xAAAA never equals it < 1024; stale
  // cross-launch tags only match for the same deterministic it -> no memset).
  unsigned* ctrl = (unsigned*)d_ws;
  unsigned long long* slots = (unsigned long long*)((char*)d_ws + 1024);
  hipMemsetAsync(d_ws, 0, 64, stream);
  fps_kernel<<<dim3(kBlocks), dim3(kThreads), 0, stream>>>(pts, out, slots, ctrl);
}

// Round 2
// 1488.748 us; speedup vs baseline: 1.2294x; 1.2294x over previous
//
#include <hip/hip_runtime.h>

// Furthest Point Sampling, B=8, C=3, N=65536, NUM_POINTS=1024.
//
// R11 = R9's proven transport (16 publishers, 16 polling waves, XCD-measured
// placement, L2 line A + IC line B fallback) with the serial chain around it
// rebuilt at VALU speed.
//
// Post-mortem of R10 (wave-autonomous, 64 slots): dur 1663->1830us,
// WRITE_SIZE 4x, VALUBusy DOWN -> the extra publishers/pollers slowed the L2
// exchange itself (read/write ping-pong on the coherence lines). Conclusion:
// the transport is contention-sensitive; 16 publishers + 16 polling waves
// (one line) is the measured optimum. REVERTED to R9 transport.
//
// What R11 changes (transport untouched):
//  * All shuffle butterflies (6-step wave, 2-step block, 4-step slot) were
//    u64 __shfl_xor chains = 24 dependent ds_bpermute ops ~ 700cy/iter.
//    Replaced with DPP reduces (pure VALU):
//      - wave:  row_shr:1/2/4/8 + row_bcast15 + row_bcast31, result lane 63,
//               broadcast via v_readlane -> SGPR key.
//      - block: 2x quad_perm xor (lanes hold s_wkey[lane&3]).
//      - slots: quad_perm xor1/xor2 + row_half_mirror + row_mirror
//               (= xor1,2,7,15 within each 16-lane row; rows replicate the 16
//               slots, so every lane ends with the global winner).
//    For unsigned-max, DPP invalid-lane/bound_ctrl semantics are harmless
//    (max with own value or with 0 are both no-ops), so no masks needed.
//  * Speculative coord gather (the sound part of R10): after poll exit each
//    lane gathers its slot-candidate's x/y/z; loads complete under the
//    VALU-only slot reduce; winner coords extracted with ballot + 3
//    v_readlane (~30cy) instead of a dependent ~250cy uniform load.
//  * Coords ride the LDS mailbox: wave 0 writes (qx,qy,qz) + release-tagged
//    word; waves 1-3 acquire the tag and read coords from LDS (~50cy)
//    instead of each paying a ~250cy L2 coord load after the tag.
//
// Placement (init, once, unchanged): 256 blocks; each reads its physical XCD
// id via s_getreg(HW_REG_XCC_ID) and registers on a per-XCD counter; first 16
// registrants on XCD j own batch j. Late blocks become spares covering
// vacancies (cross-XCD, served by the IC fallback line). Unneeded spares exit.
//
// Regions rotate mod 16, tag-validated (key low 16 bits == it; block skew < 2
// iterations << 16; 0xAA poison = tag 0xAAAA never matches it < 1024) -> no
// slot memset (only the 64B ctrl block is zeroed per launch).
//
// Key packing (idx < 65536): dist_bits(32) | (0xFFFF - idx)(16) | it(16).
// Max key = max dist, tie -> smaller index == jnp.argmax first-occurrence
// (dist >= 0 -> float bits monotone; same tag on all keys of an iteration).
// Distance math: __fmul_rn/__fadd_rn (no FMA contraction) to bit-match numpy.

namespace {

constexpr int kB = 8;
constexpr int kN = 65536;
constexpr int kNP = 1024;
constexpr int kPB = 16;                      // slices (blocks) per batch
constexpr int kThreads = 256;
constexpr int kPPT = kN / (kPB * kThreads);  // 16 points per thread
constexpr int kGrp = kPPT / 4;               // 4 float4 groups
constexpr int kWaves = kThreads / 64;        // 4
constexpr int kRgn = 16;                     // region reuse depth (skew < 2)
constexpr int kRgnStride = 32;               // u64: [0:16)=line A (L2), [16:32)=line B (IC)
constexpr int kBlocks = 256;

// One DPP max-reduce step on a u64 key. CTRL is a DPP control immediate.
// Invalid-lane handling: old = own value and bound_ctrl=false -> lanes with
// no source keep their own key; if the toolchain maps bound_ctrl to
// "write 0", max(key, 0) is also a no-op for unsigned keys. Either way the
// reduce is correct without row/bank masks.
template <int CTRL>
__device__ __forceinline__ unsigned long long dpp_max_u64(unsigned long long k) {
  const int lo = (int)(unsigned)k;
  const int hi = (int)(unsigned)(k >> 32);
  const unsigned plo = (unsigned)__builtin_amdgcn_update_dpp(lo, lo, CTRL, 0xF, 0xF, false);
  const unsigned phi = (unsigned)__builtin_amdgcn_update_dpp(hi, hi, CTRL, 0xF, 0xF, false);
  const unsigned long long p = ((unsigned long long)phi << 32) | plo;
  return p > k ? p : k;
}

// sc0 load: bypass L1, served by this XCD's L2 (the intra-XCD coherence point).
__device__ __forceinline__ unsigned long long load_l2(const unsigned long long* p) {
  unsigned long long v;
  asm volatile("global_load_dwordx2 %0, %1, off sc0\n\ts_waitcnt vmcnt(0)"
               : "=v"(v)
               : "v"(p)
               : "memory");
  return v;
}

// sc0 store: write-through to this XCD's L2.
__device__ __forceinline__ void store_l2(unsigned long long* p, unsigned long long v) {
  asm volatile("global_store_dwordx2 %0, %1, off sc0" ::"v"(p), "v"(v) : "memory");
}

__global__ __launch_bounds__(kThreads) void fps_kernel(const float* __restrict__ pts,
                                                       float* __restrict__ out,
                                                       unsigned long long* __restrict__ slots,
                                                       unsigned* __restrict__ ctrl) {
  // ctrl: [0:8) per-XCD registration counters, [8] done count, [9] spare rank.
  const int tid = threadIdx.x;
  const int lane = tid & 63;
  const int wave = tid >> 6;

  __shared__ int s_batch, s_slice;
  __shared__ unsigned long long s_wkey[kWaves];
  __shared__ unsigned s_win[2];   // parity mailbox tag: (wi << 16) | it
  __shared__ float s_qc[2][3];    // parity mailbox coords (released by s_win)
  __shared__ int s_hist[kNP];

  if (tid == 0) {
    unsigned xcc;
    asm volatile("s_getreg_b32 %0, hwreg(HW_REG_XCC_ID)" : "=s"(xcc));
    const int home = (int)(xcc & 7u);
    int batch = -1, slice = -1;
    const int pos = (int)atomicAdd(&ctrl[home], 1u);
    if (pos < kPB) {
      batch = home;
      slice = pos;
    }
    __hip_atomic_fetch_add(&ctrl[8], 1u, __ATOMIC_RELEASE, __HIP_MEMORY_SCOPE_AGENT);
    if (batch < 0) {
      while (__hip_atomic_load(&ctrl[8], __ATOMIC_ACQUIRE, __HIP_MEMORY_SCOPE_AGENT) <
             (unsigned)kBlocks) {
        __builtin_amdgcn_s_sleep(8);
      }
      int need = (int)atomicAdd(&ctrl[9], 1u);
      for (int j = 0; j < kB; ++j) {
        int have = (int)__hip_atomic_load(&ctrl[j], __ATOMIC_RELAXED, __HIP_MEMORY_SCOPE_AGENT);
        have = have > kPB ? kPB : have;
        const int vac = kPB - have;
        if (need < vac) {
          batch = j;
          slice = have + need;
          break;
        }
        need -= vac;
      }
    }
    s_batch = batch;
    s_slice = slice;
    s_win[0] = 0xFFFFFFFFu;  // tag 0xFFFF never matches it < 1024
    s_win[1] = 0xFFFFFFFFu;
  }
  __syncthreads();

  const int batch = s_batch;
  const int slice = s_slice;
  if (batch < 0) return;  // unneeded spare

  const float* __restrict__ xb = pts + (size_t)batch * 3 * kN;
  const float* __restrict__ yb = xb + kN;
  const float* __restrict__ zb = xb + 2 * kN;

  // Register-resident coords: block owns [slice*4096, slice*4096+4096).
  const int sbase = slice * (kThreads * kPPT);
  const int base0 = sbase + tid * 4;
  float px[kPPT], py[kPPT], pz[kPPT], dist[kPPT];
#pragma unroll
  for (int g = 0; g < kGrp; ++g) {
    const int base = base0 + g * (kThreads * 4);
    const float4 vx = *reinterpret_cast<const float4*>(xb + base);
    const float4 vy = *reinterpret_cast<const float4*>(yb + base);
    const float4 vz = *reinterpret_cast<const float4*>(zb + base);
    px[g * 4 + 0] = vx.x; px[g * 4 + 1] = vx.y; px[g * 4 + 2] = vx.z; px[g * 4 + 3] = vx.w;
    py[g * 4 + 0] = vy.x; py[g * 4 + 1] = vy.y; py[g * 4 + 2] = vy.z; py[g * 4 + 3] = vy.w;
    pz[g * 4 + 0] = vz.x; pz[g * 4 + 1] = vz.y; pz[g * 4 + 2] = vz.z; pz[g * 4 + 3] = vz.w;
  }
#pragma unroll
  for (int k = 0; k < kPPT; ++k) dist[k] = 1e10f;

  // Seed: index 0 (uniform broadcast load).
  float qx = xb[0], qy = yb[0], qz = zb[0];

  unsigned long long* const sb = slots + (size_t)batch * kRgn * kRgnStride;

  for (int it = 1; it < kNP; ++it) {
    // --- update dists + per-thread argmax (ascending index, strict '>') ---
    float bd = -1.0f;
    int bi = 0;
#pragma unroll
    for (int g = 0; g < kGrp; ++g) {
#pragma unroll
      for (int j = 0; j < 4; ++j) {
        const int k = g * 4 + j;
        const float dx = px[k] - qx;
        const float dy = py[k] - qy;
        const float dz = pz[k] - qz;
        const float ss =
            __fadd_rn(__fadd_rn(__fmul_rn(dx, dx), __fmul_rn(dy, dy)), __fmul_rn(dz, dz));
        const float nd = fminf(dist[k], ss);
        dist[k] = nd;
        if (nd > bd) {
          bd = nd;
          bi = base0 + g * (kThreads * 4) + j;
        }
      }
    }

    // key: dist(32) | (0xFFFF - idx)(16) | it(16)  -- tag self-validates slots.
    unsigned long long key = ((unsigned long long)__float_as_uint(bd) << 32) |
                             ((unsigned long long)(0xFFFFu - (unsigned)bi) << 16) |
                             (unsigned long long)(unsigned)it;

    // --- wave reduce at VALU speed: row_shr 1/2/4/8 + bcast15/31 -> lane 63 ---
    key = dpp_max_u64<0x111>(key);  // row_shr:1
    key = dpp_max_u64<0x112>(key);  // row_shr:2
    key = dpp_max_u64<0x114>(key);  // row_shr:4
    key = dpp_max_u64<0x118>(key);  // row_shr:8
    key = dpp_max_u64<0x142>(key);  // row_bcast:15
    key = dpp_max_u64<0x143>(key);  // row_bcast:31
    const unsigned wklo = (unsigned)__builtin_amdgcn_readlane((int)(unsigned)key, 63);
    const unsigned wkhi = (unsigned)__builtin_amdgcn_readlane((int)(unsigned)(key >> 32), 63);
    if (lane == 0) {
      s_wkey[wave] = ((unsigned long long)wkhi << 32) | wklo;
    }
    __syncthreads();  // the only barrier in the iteration

    if (wave == 0) {
      // --- block reduce over 4 wave keys: 2x quad_perm xor ---
      unsigned long long bk = s_wkey[lane & (kWaves - 1)];
      bk = dpp_max_u64<0xB1>(bk);  // quad_perm {1,0,3,2} = xor 1
      bk = dpp_max_u64<0x4E>(bk);  // quad_perm {2,3,0,1} = xor 2

      unsigned long long* const rgn = sb + (size_t)(it & (kRgn - 1)) * kRgnStride;
      if (lane == 0) {
        store_l2(rgn + slice, bk);  // primary: XCD-local L2 (measured co-location)
        __hip_atomic_store(rgn + kPB + slice, bk, __ATOMIC_RELAXED,
                           __HIP_MEMORY_SCOPE_AGENT);  // fallback: IC
      }

      // --- poll line A from round 0; merge IC line B from round 2 ---
      unsigned long long sv;
      int round = 0;
      for (;;) {
        unsigned long long a = load_l2(rgn + (lane & (kPB - 1)));
        bool ok = (unsigned)(a & 0xFFFFull) == (unsigned)it;
        if (round >= 2 && !ok) {
          const unsigned long long fb = __hip_atomic_load(
              rgn + kPB + (lane & (kPB - 1)), __ATOMIC_RELAXED, __HIP_MEMORY_SCOPE_AGENT);
          if ((unsigned)(fb & 0xFFFFull) == (unsigned)it) {
            a = fb;
            ok = true;
          }
        }
        if (__all(ok)) {
          sv = a;
          break;
        }
        ++round;
      }

      // --- speculative candidate-coord gather: issued before the VALU-only
      //     slot reduce; the loads complete underneath it ---
      const int cand = (int)(0xFFFFu - ((unsigned)(sv >> 16) & 0xFFFFu));
      const float gx = xb[cand];
      const float gy = yb[cand];
      const float gz = zb[cand];

      // --- 16-slot reduce: xor1, xor2, xor7(half-mirror), xor15(mirror);
      //     every 16-lane row holds all 16 slots -> all lanes get the winner ---
      unsigned long long k2 = sv;
      k2 = dpp_max_u64<0xB1>(k2);   // quad_perm xor 1
      k2 = dpp_max_u64<0x4E>(k2);   // quad_perm xor 2
      k2 = dpp_max_u64<0x141>(k2);  // row_half_mirror = xor 7
      k2 = dpp_max_u64<0x140>(k2);  // row_mirror = xor 15

      // Winner coords: exactly the lanes whose slot held k2 match; pull their
      // speculative gather via readlane (src is wave-uniform).
      const unsigned long long m = __ballot(sv == k2);
      const int src = (int)__ffsll(m) - 1;
      qx = __int_as_float(__builtin_amdgcn_readlane(__float_as_int(gx), src));
      qy = __int_as_float(__builtin_amdgcn_readlane(__float_as_int(gy), src));
      qz = __int_as_float(__builtin_amdgcn_readlane(__float_as_int(gz), src));

      const int wi = (int)(0xFFFFu - ((unsigned)(k2 >> 16) & 0xFFFFu));
      if (lane == 0) {
        s_hist[it] = wi;
        s_qc[it & 1][0] = qx;
        s_qc[it & 1][1] = qy;
        s_qc[it & 1][2] = qz;
        __hip_atomic_store(&s_win[it & 1], ((unsigned)wi << 16) | (unsigned)it,
                           __ATOMIC_RELEASE, __HIP_MEMORY_SCOPE_WORKGROUP);
      }
    } else {
      // --- non-leader waves: spin on the LDS mailbox; coords come from LDS
      //     (released by the tag store), not from a ~250cy L2 load ---
      unsigned v;
      do {
        v = __hip_atomic_load(&s_win[it & 1], __ATOMIC_ACQUIRE, __HIP_MEMORY_SCOPE_WORKGROUP);
      } while ((v & 0xFFFFu) != (unsigned)it);
      qx = s_qc[it & 1][0];
      qy = s_qc[it & 1][1];
      qz = s_qc[it & 1][2];
    }
  }

  __syncthreads();  // make s_hist (written by wave 0) visible to all waves

  // --- gather: out[b][c][j] = points[b][c][idx_j]; slice-0 block per batch ---
  if (slice == 0) {
    float* __restrict__ ob = out + (size_t)batch * 3 * kNP;
    for (int j = tid; j < kNP; j += kThreads) {
      const int id = (j == 0) ? 0 : s_hist[j];
      ob[j] = xb[id];
      ob[kNP + j] = yb[id];
      ob[2 * kNP + j] = zb[id];
    }
  }
}

}  // namespace

extern "C" void kernel_launch(void* const* d_in, const int* in_sizes, int n_in,
                              void* d_out, int out_size, void* d_ws, size_t ws_size,
                              hipStream_t stream) {
  (void)in_sizes;
  (void)n_in;
  (void)out_size;
  (void)ws_size;
  const float* pts = (const float*)d_in[0];
  float* out = (float*)d_out;
  // ws: [0,64) ctrl (zeroed per launch), [1024, 1024+32K) slot regions
  // (tag-validated: 0xAA poison -> tag 0xAAAA never equals it < 1024 -> no memset).
  unsigned* ctrl = (unsigned*)d_ws;
  unsigned long long* slots = (unsigned long long*)((char*)d_ws + 1024);
  hipMemsetAsync(d_ws, 0, 64, stream);
  fps_kernel<<<dim3(kBlocks), dim3(kThreads), 0, stream>>>(pts, out, slots, ctrl);
}